// Round 15
// baseline (53.919 us; speedup 1.0000x reference)
//
#include <hip/hip_runtime.h>
#include <math.h>

#define D 64
#define NC 8
#define FK 8
#define NMIN 1440
#define SLOTCAP 256          // mean 91 items/bucket, 17-sigma headroom
#define TWO_PI_F 6.28318530717958647692f

#define TSZ ((size_t)NMIN * NC * D)   // table floats (2.95 MB)

// ---------------------------------------------------------------------------
// Kernel 1: build per-minute Fourier table T[m][n][d] (single copy).
// ---------------------------------------------------------------------------
__global__ __launch_bounds__(256) void build_table_kernel(
    const float* __restrict__ a0,
    const float* __restrict__ fa,
    const float* __restrict__ fb,
    float* __restrict__ T)
{
    const int m = blockIdx.x;
    const int t = threadIdx.x;
    const int d  = t & (D - 1);
    const int n0 = t >> 6;
    const float angle = (float)m * (TWO_PI_F / (float)(NMIN - 1));

    float c[FK], s[FK];
    float s1, c1;
    sincosf(angle, &s1, &c1);
    c[0] = c1; s[0] = s1;
    {
        const float tw = 2.0f * c1;
        float cp = 1.0f, sp = 0.0f;
        float cc = c1, ss = s1;
#pragma unroll
        for (int k = 1; k < FK; ++k) {
            const float cn = fmaf(tw, cc, -cp);
            const float sn = fmaf(tw, ss, -sp);
            cp = cc; sp = ss; cc = cn; ss = sn;
            c[k] = cc; s[k] = ss;
        }
    }

#pragma unroll
    for (int j = 0; j < 2; ++j) {
        const int n = n0 + 4 * j;
        float v = a0[n * D + d];
#pragma unroll
        for (int k = 0; k < FK; ++k) {
            v = fmaf(c[k], fa[(n * FK + k) * D + d], v);
            v = fmaf(s[k], fb[(n * FK + k) * D + d], v);
        }
        T[(size_t)(m * NC + n) * D + d] = v;
    }
}

// ---------------------------------------------------------------------------
// Kernel B: bucket items by minute. slots[m][pos] = item index.
// Same minute formula as the reference (and rounds 4-12).
// ---------------------------------------------------------------------------
__global__ __launch_bounds__(256) void bucket_kernel(
    const float* __restrict__ thetas,
    int* __restrict__ cnt,
    int* __restrict__ slots,
    int B)
{
    const int b = blockIdx.x * 256 + threadIdx.x;
    if (b >= B) return;
    const float th = thetas[b];
    int m = (int)((th / TWO_PI_F) * (float)NMIN);
    m = m < 0 ? 0 : (m > NMIN - 1 ? NMIN - 1 : m);
    const int pos = atomicAdd(&cnt[m], 1);
    if (pos < SLOTCAP) slots[m * SLOTCAP + pos] = b;
}

// ---------------------------------------------------------------------------
// 8-lane all-reduce sum on the VALU via DPP (groups are 8-lane aligned).
// ---------------------------------------------------------------------------
__device__ __forceinline__ float grp8_allreduce_sum(float v) {
    int t;
    t = __builtin_amdgcn_update_dpp(0, __float_as_int(v), 0xB1, 0xF, 0xF, true);
    v += __int_as_float(t);
    t = __builtin_amdgcn_update_dpp(0, __float_as_int(v), 0x4E, 0xF, 0xF, true);
    v += __int_as_float(t);
    t = __builtin_amdgcn_update_dpp(0, __float_as_int(v), 0x141, 0xF, 0xF, true);
    v += __int_as_float(t);
    return v;
}

// ---------------------------------------------------------------------------
// Kernel 2: one block per minute bucket. All items in the block share T[m]
// (2 KB -> L1-resident after first touch; kills the 268 MB random L2 gather).
// 32 groups x 8 lanes; group g handles slot it = g, g+32, ... Lane j owns
// float4 d-slices j and j+8. proto in LDS; DPP reduce; softmax in registers.
// ---------------------------------------------------------------------------
__global__ __launch_bounds__(256) void mix_bucket_kernel(
    const float* __restrict__ emb,
    const float* __restrict__ proto,
    const float* __restrict__ T,
    const int* __restrict__ cnt,
    const int* __restrict__ slots,
    float* __restrict__ out_emb,
    float* __restrict__ out_P)
{
    __shared__ float4 sproto[NC * (D / 4)];      // 2 KB
    if (threadIdx.x < NC * (D / 4)) {
        sproto[threadIdx.x] = ((const float4*)proto)[threadIdx.x];
    }
    __syncthreads();

    const int m = blockIdx.x;
    int count = cnt[m];
    if (count > SLOTCAP) count = SLOTCAP;

    const int g = threadIdx.x >> 3;  // group 0..31
    const int j = threadIdx.x & 7;   // lane in group
    const float4* __restrict__ t4 = (const float4*)(T + (size_t)m * NC * D);
    const int* __restrict__ bslots = slots + m * SLOTCAP;

    for (int it = g; it < count; it += 32) {
        const int b = bslots[it];        // 8 lanes same addr -> broadcast

        // --- emb slices (two 128B segments per item) ---
        const float4* __restrict__ e4 = (const float4*)emb + (size_t)b * (D / 4);
        const float4 ev0 = e4[j];
        const float4 ev1 = e4[j + 8];

        // --- partial scores vs 8 prototypes (from LDS) ---
        float sc[NC];
#pragma unroll
        for (int n = 0; n < NC; ++n) {
            const float4 pa = sproto[n * (D / 4) + j];
            const float4 pb = sproto[n * (D / 4) + j + 8];
            float v = ev0.x * pa.x;
            v = fmaf(ev0.y, pa.y, v);
            v = fmaf(ev0.z, pa.z, v);
            v = fmaf(ev0.w, pa.w, v);
            v = fmaf(ev1.x, pb.x, v);
            v = fmaf(ev1.y, pb.y, v);
            v = fmaf(ev1.z, pb.z, v);
            v = fmaf(ev1.w, pb.w, v);
            sc[n] = v;
        }

        // --- reduce across the 8-lane group (VALU/DPP) ---
#pragma unroll
        for (int n = 0; n < NC; ++n) {
            sc[n] = grp8_allreduce_sum(sc[n]);
        }

        // --- softmax(scores / tau), tau = 0.2 -> *5 ---
        float mx = -1e30f;
#pragma unroll
        for (int n = 0; n < NC; ++n) { sc[n] *= 5.0f; mx = fmaxf(mx, sc[n]); }
        float sum = 0.0f;
#pragma unroll
        for (int n = 0; n < NC; ++n) { sc[n] = __expf(sc[n] - mx); sum += sc[n]; }
        const float inv = 1.0f / sum;
#pragma unroll
        for (int n = 0; n < NC; ++n) sc[n] *= inv;

        // --- T[m] mix: same 2KB for the whole block -> L1-hot ---
        float4 acc0 = make_float4(0.f, 0.f, 0.f, 0.f);
        float4 acc1 = make_float4(0.f, 0.f, 0.f, 0.f);
#pragma unroll
        for (int n = 0; n < NC; ++n) {
            const float4 ta = t4[n * (D / 4) + j];
            const float4 tb = t4[n * (D / 4) + j + 8];
            const float pw = sc[n];
            acc0.x = fmaf(pw, ta.x, acc0.x);
            acc0.y = fmaf(pw, ta.y, acc0.y);
            acc0.z = fmaf(pw, ta.z, acc0.z);
            acc0.w = fmaf(pw, ta.w, acc0.w);
            acc1.x = fmaf(pw, tb.x, acc1.x);
            acc1.y = fmaf(pw, tb.y, acc1.y);
            acc1.z = fmaf(pw, tb.z, acc1.z);
            acc1.w = fmaf(pw, tb.w, acc1.w);
        }

        float4* __restrict__ o4 = (float4*)out_emb + (size_t)b * (D / 4);
        o4[j]     = acc0;
        o4[j + 8] = acc1;

        if (j == 0) {
            ((float4*)out_P)[(size_t)b * 2 + 0] = make_float4(sc[0], sc[1], sc[2], sc[3]);
        } else if (j == 4) {
            ((float4*)out_P)[(size_t)b * 2 + 1] = make_float4(sc[4], sc[5], sc[6], sc[7]);
        }
    }
}

// ---------------------------------------------------------------------------
// Fallback (only if ws_size too small): fully fused, coefficients in LDS.
// ---------------------------------------------------------------------------
__global__ __launch_bounds__(256) void fused_fallback(
    const float* __restrict__ emb,
    const float* __restrict__ thetas,
    const float* __restrict__ proto,
    const float* __restrict__ a0,
    const float* __restrict__ fa,
    const float* __restrict__ fb,
    float* __restrict__ out_emb,
    float* __restrict__ out_P,
    int B)
{
    __shared__ float sp[NC * D];
    __shared__ float sa0[NC * D];
    __shared__ float sfa[NC * FK * D];
    __shared__ float sfb[NC * FK * D];
    for (int i = threadIdx.x; i < NC * D; i += 256) { sp[i] = proto[i]; sa0[i] = a0[i]; }
    for (int i = threadIdx.x; i < NC * FK * D; i += 256) { sfa[i] = fa[i]; sfb[i] = fb[i]; }
    __syncthreads();

    const int b = blockIdx.x * 256 + threadIdx.x;
    if (b >= B) return;

    const float4* __restrict__ e4  = (const float4*)(emb + (size_t)b * D);
    const float4* sp4  = (const float4*)sp;
    const float4* sa04 = (const float4*)sa0;
    const float4* sfa4 = (const float4*)sfa;
    const float4* sfb4 = (const float4*)sfb;

    float sc[NC];
#pragma unroll
    for (int n = 0; n < NC; ++n) sc[n] = 0.0f;
#pragma unroll
    for (int i = 0; i < D / 4; ++i) {
        const float4 ev = e4[i];
#pragma unroll
        for (int n = 0; n < NC; ++n) {
            const float4 pv = sp4[n * (D / 4) + i];
            sc[n] = fmaf(ev.x, pv.x, sc[n]);
            sc[n] = fmaf(ev.y, pv.y, sc[n]);
            sc[n] = fmaf(ev.z, pv.z, sc[n]);
            sc[n] = fmaf(ev.w, pv.w, sc[n]);
        }
    }
    float mx = -1e30f;
#pragma unroll
    for (int n = 0; n < NC; ++n) { sc[n] *= 5.0f; mx = fmaxf(mx, sc[n]); }
    float sum = 0.0f;
#pragma unroll
    for (int n = 0; n < NC; ++n) { sc[n] = __expf(sc[n] - mx); sum += sc[n]; }
    const float inv = 1.0f / sum;
#pragma unroll
    for (int n = 0; n < NC; ++n) sc[n] *= inv;

    const float th = thetas[b];
    int m = (int)((th / TWO_PI_F) * (float)NMIN);
    m = m < 0 ? 0 : (m > NMIN - 1 ? NMIN - 1 : m);
    const float angle = (float)m * (TWO_PI_F / (float)(NMIN - 1));
    float c[FK], s[FK];
#pragma unroll
    for (int k = 0; k < FK; ++k) sincosf(angle * (float)(k + 1), &s[k], &c[k]);

    float4 acc[D / 4];
#pragma unroll
    for (int i = 0; i < D / 4; ++i) acc[i] = make_float4(0.f, 0.f, 0.f, 0.f);
#pragma unroll
    for (int n = 0; n < NC; ++n) {
        const float pw = sc[n];
#pragma unroll
        for (int i = 0; i < D / 4; ++i) {
            float4 v = sa04[n * (D / 4) + i];
#pragma unroll
            for (int k = 0; k < FK; ++k) {
                const float4 av = sfa4[(n * FK + k) * (D / 4) + i];
                const float4 bv = sfb4[(n * FK + k) * (D / 4) + i];
                v.x = fmaf(c[k], av.x, v.x); v.x = fmaf(s[k], bv.x, v.x);
                v.y = fmaf(c[k], av.y, v.y); v.y = fmaf(s[k], bv.y, v.y);
                v.z = fmaf(c[k], av.z, v.z); v.z = fmaf(s[k], bv.z, v.z);
                v.w = fmaf(c[k], av.w, v.w); v.w = fmaf(s[k], bv.w, v.w);
            }
            acc[i].x = fmaf(pw, v.x, acc[i].x);
            acc[i].y = fmaf(pw, v.y, acc[i].y);
            acc[i].z = fmaf(pw, v.z, acc[i].z);
            acc[i].w = fmaf(pw, v.w, acc[i].w);
        }
    }
    float4* o4 = (float4*)(out_emb + (size_t)b * D);
#pragma unroll
    for (int i = 0; i < D / 4; ++i) o4[i] = acc[i];
    float4* op = (float4*)(out_P + (size_t)b * NC);
    op[0] = make_float4(sc[0], sc[1], sc[2], sc[3]);
    op[1] = make_float4(sc[4], sc[5], sc[6], sc[7]);
}

extern "C" void kernel_launch(void* const* d_in, const int* in_sizes, int n_in,
                              void* d_out, int out_size, void* d_ws, size_t ws_size,
                              hipStream_t stream)
{
    const float* emb    = (const float*)d_in[0];
    const float* thetas = (const float*)d_in[1];
    const float* proto  = (const float*)d_in[2];
    const float* a0     = (const float*)d_in[3];
    const float* fa     = (const float*)d_in[4];
    const float* fb     = (const float*)d_in[5];

    const int B = in_sizes[0] / D;           // 131072
    float* out_emb = (float*)d_out;
    float* out_P   = (float*)d_out + (size_t)B * D;

    // workspace layout: T (2.95MB) | cnt (1440 int) | slots (1440*256 int)
    const size_t need_bytes = TSZ * sizeof(float)
                            + (size_t)NMIN * sizeof(int)
                            + (size_t)NMIN * SLOTCAP * sizeof(int);

    if (ws_size >= need_bytes) {
        float* T    = (float*)d_ws;
        int* cnt    = (int*)(T + TSZ);
        int* slots  = cnt + NMIN;

        hipMemsetAsync(cnt, 0, (size_t)NMIN * sizeof(int), stream);
        build_table_kernel<<<NMIN, 256, 0, stream>>>(a0, fa, fb, T);
        bucket_kernel<<<(B + 255) / 256, 256, 0, stream>>>(thetas, cnt, slots, B);
        mix_bucket_kernel<<<NMIN, 256, 0, stream>>>(emb, proto, T, cnt, slots,
                                                    out_emb, out_P);
    } else {
        const int blocks = (B + 255) / 256;
        fused_fallback<<<blocks, 256, 0, stream>>>(emb, thetas, proto, a0, fa, fb,
                                                   out_emb, out_P, B);
    }
}

// Round 16
// 27.658 us; speedup vs baseline: 1.9495x; 1.9495x over previous
//
#include <hip/hip_runtime.h>
#include <hip/hip_fp16.h>
#include <math.h>

#define D 64
#define NC 8
#define FK 8
#define NMIN 1440
#define TWO_PI_F 6.28318530717958647692f

#define TSZ ((size_t)NMIN * NC * D)   // table elements

// ---------------------------------------------------------------------------
// Kernel 1: build per-minute Fourier table T[m][n][d], stored as fp16.
// Compute in fp32 (Chebyshev recurrence), round once to half on store.
// ---------------------------------------------------------------------------
__global__ __launch_bounds__(256) void build_table_kernel(
    const float* __restrict__ a0,
    const float* __restrict__ fa,
    const float* __restrict__ fb,
    __half* __restrict__ T)
{
    const int m = blockIdx.x;
    const int t = threadIdx.x;
    const int d  = t & (D - 1);
    const int n0 = t >> 6;
    const float angle = (float)m * (TWO_PI_F / (float)(NMIN - 1));

    float c[FK], s[FK];
    float s1, c1;
    sincosf(angle, &s1, &c1);
    c[0] = c1; s[0] = s1;
    {
        const float tw = 2.0f * c1;
        float cp = 1.0f, sp = 0.0f;
        float cc = c1, ss = s1;
#pragma unroll
        for (int k = 1; k < FK; ++k) {
            const float cn = fmaf(tw, cc, -cp);
            const float sn = fmaf(tw, ss, -sp);
            cp = cc; sp = ss; cc = cn; ss = sn;
            c[k] = cc; s[k] = ss;
        }
    }

#pragma unroll
    for (int j = 0; j < 2; ++j) {
        const int n = n0 + 4 * j;
        float v = a0[n * D + d];
#pragma unroll
        for (int k = 0; k < FK; ++k) {
            v = fmaf(c[k], fa[(n * FK + k) * D + d], v);
            v = fmaf(s[k], fb[(n * FK + k) * D + d], v);
        }
        T[(size_t)(m * NC + n) * D + d] = __float2half(v);
    }
}

// ---------------------------------------------------------------------------
// 8-lane all-reduce sum on the VALU via DPP (groups are 8-lane aligned).
// ---------------------------------------------------------------------------
__device__ __forceinline__ float grp8_allreduce_sum(float v) {
    int t;
    t = __builtin_amdgcn_update_dpp(0, __float_as_int(v), 0xB1, 0xF, 0xF, true);
    v += __int_as_float(t);
    t = __builtin_amdgcn_update_dpp(0, __float_as_int(v), 0x4E, 0xF, 0xF, true);
    v += __int_as_float(t);
    t = __builtin_amdgcn_update_dpp(0, __float_as_int(v), 0x141, 0xF, 0xF, true);
    v += __int_as_float(t);
    return v;
}

// ---------------------------------------------------------------------------
// Kernel 2: 8 lanes per item; proto in LDS; DPP reduce; fp16 T gather
// (single change vs round 12: T is half, two uint2 loads per n instead of
// two float4 -> halves the dominant L1/L2 gather traffic).
// Lane j owns d-slices 4j..4j+3 and 32+4j..35+4j (same as round 12).
// ---------------------------------------------------------------------------
__global__ __launch_bounds__(256) void mix_kernel8(
    const float* __restrict__ emb,
    const float* __restrict__ thetas,
    const float* __restrict__ proto,
    const __half* __restrict__ T,
    float* __restrict__ out_emb,
    float* __restrict__ out_P,
    int B)
{
    __shared__ float4 sproto[NC * (D / 4)];      // 2 KB
    if (threadIdx.x < NC * (D / 4)) {
        sproto[threadIdx.x] = ((const float4*)proto)[threadIdx.x];
    }
    __syncthreads();

    const int t = blockIdx.x * 256 + threadIdx.x;
    const int b = t >> 3;            // item index
    const int j = t & 7;             // lane-in-group
    if (b >= B) return;

    // --- minute bucket early ---
    const float th = thetas[b];                  // broadcast within group
    int m = (int)((th / TWO_PI_F) * (float)NMIN);
    m = m < 0 ? 0 : (m > NMIN - 1 ? NMIN - 1 : m);

    // --- emb slices (coalesced) ---
    const float4* __restrict__ e4 = (const float4*)emb + (size_t)b * (D / 4);
    const float4 ev0 = e4[j];
    const float4 ev1 = e4[j + 8];

    // --- partial scores vs 8 prototypes (from LDS) ---
    float sc[NC];
#pragma unroll
    for (int n = 0; n < NC; ++n) {
        const float4 pa = sproto[n * (D / 4) + j];
        const float4 pb = sproto[n * (D / 4) + j + 8];
        float v = ev0.x * pa.x;
        v = fmaf(ev0.y, pa.y, v);
        v = fmaf(ev0.z, pa.z, v);
        v = fmaf(ev0.w, pa.w, v);
        v = fmaf(ev1.x, pb.x, v);
        v = fmaf(ev1.y, pb.y, v);
        v = fmaf(ev1.z, pb.z, v);
        v = fmaf(ev1.w, pb.w, v);
        sc[n] = v;
    }

    // --- reduce across the 8-lane group (VALU/DPP) ---
#pragma unroll
    for (int n = 0; n < NC; ++n) {
        sc[n] = grp8_allreduce_sum(sc[n]);
    }

    // --- softmax(scores / tau), tau = 0.2 -> *5 ---
    float mx = -1e30f;
#pragma unroll
    for (int n = 0; n < NC; ++n) { sc[n] *= 5.0f; mx = fmaxf(mx, sc[n]); }
    float sum = 0.0f;
#pragma unroll
    for (int n = 0; n < NC; ++n) { sc[n] = __expf(sc[n] - mx); sum += sc[n]; }
    const float inv = 1.0f / sum;
#pragma unroll
    for (int n = 0; n < NC; ++n) sc[n] *= inv;

    // --- gather fp16 T[m] rows (uint2 = 4 halves per slice) and mix ---
    // row = 64 halves = 32B*4; lane j takes uint2 idx j (d 4j..4j+3) and
    // idx j+8 (d 32+4j..35+4j): same ownership/coalescing as round 12.
    const uint2* __restrict__ t2 = (const uint2*)(T + (size_t)m * NC * D);
    float4 acc0 = make_float4(0.f, 0.f, 0.f, 0.f);
    float4 acc1 = make_float4(0.f, 0.f, 0.f, 0.f);
#pragma unroll
    for (int n = 0; n < NC; ++n) {
        const uint2 ua = t2[n * 16 + j];
        const uint2 ub = t2[n * 16 + j + 8];
        const float pw = sc[n];
        const float2 a01 = __half22float2(*(const __half2*)&ua.x);
        const float2 a23 = __half22float2(*(const __half2*)&ua.y);
        const float2 b01 = __half22float2(*(const __half2*)&ub.x);
        const float2 b23 = __half22float2(*(const __half2*)&ub.y);
        acc0.x = fmaf(pw, a01.x, acc0.x);
        acc0.y = fmaf(pw, a01.y, acc0.y);
        acc0.z = fmaf(pw, a23.x, acc0.z);
        acc0.w = fmaf(pw, a23.y, acc0.w);
        acc1.x = fmaf(pw, b01.x, acc1.x);
        acc1.y = fmaf(pw, b01.y, acc1.y);
        acc1.z = fmaf(pw, b23.x, acc1.z);
        acc1.w = fmaf(pw, b23.y, acc1.w);
    }

    float4* __restrict__ o4 = (float4*)out_emb + (size_t)b * (D / 4);
    o4[j]     = acc0;
    o4[j + 8] = acc1;

    // --- P output: lanes 0 and 4 each write one float4 ---
    if (j == 0) {
        ((float4*)out_P)[(size_t)b * 2 + 0] = make_float4(sc[0], sc[1], sc[2], sc[3]);
    } else if (j == 4) {
        ((float4*)out_P)[(size_t)b * 2 + 1] = make_float4(sc[4], sc[5], sc[6], sc[7]);
    }
}

// ---------------------------------------------------------------------------
// Fallback (only if ws_size too small): fully fused, coefficients in LDS.
// ---------------------------------------------------------------------------
__global__ __launch_bounds__(256) void fused_fallback(
    const float* __restrict__ emb,
    const float* __restrict__ thetas,
    const float* __restrict__ proto,
    const float* __restrict__ a0,
    const float* __restrict__ fa,
    const float* __restrict__ fb,
    float* __restrict__ out_emb,
    float* __restrict__ out_P,
    int B)
{
    __shared__ float sp[NC * D];
    __shared__ float sa0[NC * D];
    __shared__ float sfa[NC * FK * D];
    __shared__ float sfb[NC * FK * D];
    for (int i = threadIdx.x; i < NC * D; i += 256) { sp[i] = proto[i]; sa0[i] = a0[i]; }
    for (int i = threadIdx.x; i < NC * FK * D; i += 256) { sfa[i] = fa[i]; sfb[i] = fb[i]; }
    __syncthreads();

    const int b = blockIdx.x * 256 + threadIdx.x;
    if (b >= B) return;

    const float4* __restrict__ e4  = (const float4*)(emb + (size_t)b * D);
    const float4* sp4  = (const float4*)sp;
    const float4* sa04 = (const float4*)sa0;
    const float4* sfa4 = (const float4*)sfa;
    const float4* sfb4 = (const float4*)sfb;

    float sc[NC];
#pragma unroll
    for (int n = 0; n < NC; ++n) sc[n] = 0.0f;
#pragma unroll
    for (int i = 0; i < D / 4; ++i) {
        const float4 ev = e4[i];
#pragma unroll
        for (int n = 0; n < NC; ++n) {
            const float4 pv = sp4[n * (D / 4) + i];
            sc[n] = fmaf(ev.x, pv.x, sc[n]);
            sc[n] = fmaf(ev.y, pv.y, sc[n]);
            sc[n] = fmaf(ev.z, pv.z, sc[n]);
            sc[n] = fmaf(ev.w, pv.w, sc[n]);
        }
    }
    float mx = -1e30f;
#pragma unroll
    for (int n = 0; n < NC; ++n) { sc[n] *= 5.0f; mx = fmaxf(mx, sc[n]); }
    float sum = 0.0f;
#pragma unroll
    for (int n = 0; n < NC; ++n) { sc[n] = __expf(sc[n] - mx); sum += sc[n]; }
    const float inv = 1.0f / sum;
#pragma unroll
    for (int n = 0; n < NC; ++n) sc[n] *= inv;

    const float th = thetas[b];
    int m = (int)((th / TWO_PI_F) * (float)NMIN);
    m = m < 0 ? 0 : (m > NMIN - 1 ? NMIN - 1 : m);
    const float angle = (float)m * (TWO_PI_F / (float)(NMIN - 1));
    float c[FK], s[FK];
#pragma unroll
    for (int k = 0; k < FK; ++k) sincosf(angle * (float)(k + 1), &s[k], &c[k]);

    float4 acc[D / 4];
#pragma unroll
    for (int i = 0; i < D / 4; ++i) acc[i] = make_float4(0.f, 0.f, 0.f, 0.f);
#pragma unroll
    for (int n = 0; n < NC; ++n) {
        const float pw = sc[n];
#pragma unroll
        for (int i = 0; i < D / 4; ++i) {
            float4 v = sa04[n * (D / 4) + i];
#pragma unroll
            for (int k = 0; k < FK; ++k) {
                const float4 av = sfa4[(n * FK + k) * (D / 4) + i];
                const float4 bv = sfb4[(n * FK + k) * (D / 4) + i];
                v.x = fmaf(c[k], av.x, v.x); v.x = fmaf(s[k], bv.x, v.x);
                v.y = fmaf(c[k], av.y, v.y); v.y = fmaf(s[k], bv.y, v.y);
                v.z = fmaf(c[k], av.z, v.z); v.z = fmaf(s[k], bv.z, v.z);
                v.w = fmaf(c[k], av.w, v.w); v.w = fmaf(s[k], bv.w, v.w);
            }
            acc[i].x = fmaf(pw, v.x, acc[i].x);
            acc[i].y = fmaf(pw, v.y, acc[i].y);
            acc[i].z = fmaf(pw, v.z, acc[i].z);
            acc[i].w = fmaf(pw, v.w, acc[i].w);
        }
    }
    float4* o4 = (float4*)(out_emb + (size_t)b * D);
#pragma unroll
    for (int i = 0; i < D / 4; ++i) o4[i] = acc[i];
    float4* op = (float4*)(out_P + (size_t)b * NC);
    op[0] = make_float4(sc[0], sc[1], sc[2], sc[3]);
    op[1] = make_float4(sc[4], sc[5], sc[6], sc[7]);
}

extern "C" void kernel_launch(void* const* d_in, const int* in_sizes, int n_in,
                              void* d_out, int out_size, void* d_ws, size_t ws_size,
                              hipStream_t stream)
{
    const float* emb    = (const float*)d_in[0];
    const float* thetas = (const float*)d_in[1];
    const float* proto  = (const float*)d_in[2];
    const float* a0     = (const float*)d_in[3];
    const float* fa     = (const float*)d_in[4];
    const float* fb     = (const float*)d_in[5];

    const int B = in_sizes[0] / D;           // 131072
    float* out_emb = (float*)d_out;
    float* out_P   = (float*)d_out + (size_t)B * D;

    const size_t table_bytes = TSZ * sizeof(__half);   // ~1.5 MB

    if (ws_size >= table_bytes) {
        __half* T = (__half*)d_ws;
        build_table_kernel<<<NMIN, 256, 0, stream>>>(a0, fa, fb, T);
        // 8 lanes per item: B*8 threads total
        const long long total_threads = (long long)B * 8;
        const int blocks = (int)((total_threads + 255) / 256);
        mix_kernel8<<<blocks, 256, 0, stream>>>(emb, thetas, proto, T, out_emb, out_P, B);
    } else {
        const int blocks = (B + 255) / 256;
        fused_fallback<<<blocks, 256, 0, stream>>>(emb, thetas, proto, a0, fa, fb,
                                                   out_emb, out_P, B);
    }
}

// Round 17
// 27.006 us; speedup vs baseline: 1.9965x; 1.0241x over previous
//
#include <hip/hip_runtime.h>
#include <hip/hip_fp16.h>
#include <math.h>

#define D 64
#define NC 8
#define FK 8
#define NMIN 1440
#define TWO_PI_F 6.28318530717958647692f

#define TSZ ((size_t)NMIN * NC * D)   // table elements

// ---------------------------------------------------------------------------
// Kernel 1: build per-minute Fourier table T[m][n][d], stored as fp16.
// Compute in fp32 (Chebyshev recurrence), round once to half on store.
// ---------------------------------------------------------------------------
__global__ __launch_bounds__(256) void build_table_kernel(
    const float* __restrict__ a0,
    const float* __restrict__ fa,
    const float* __restrict__ fb,
    __half* __restrict__ T)
{
    const int m = blockIdx.x;
    const int t = threadIdx.x;
    const int d  = t & (D - 1);
    const int n0 = t >> 6;
    const float angle = (float)m * (TWO_PI_F / (float)(NMIN - 1));

    float c[FK], s[FK];
    float s1, c1;
    sincosf(angle, &s1, &c1);
    c[0] = c1; s[0] = s1;
    {
        const float tw = 2.0f * c1;
        float cp = 1.0f, sp = 0.0f;
        float cc = c1, ss = s1;
#pragma unroll
        for (int k = 1; k < FK; ++k) {
            const float cn = fmaf(tw, cc, -cp);
            const float sn = fmaf(tw, ss, -sp);
            cp = cc; sp = ss; cc = cn; ss = sn;
            c[k] = cc; s[k] = ss;
        }
    }

#pragma unroll
    for (int j = 0; j < 2; ++j) {
        const int n = n0 + 4 * j;
        float v = a0[n * D + d];
#pragma unroll
        for (int k = 0; k < FK; ++k) {
            v = fmaf(c[k], fa[(n * FK + k) * D + d], v);
            v = fmaf(s[k], fb[(n * FK + k) * D + d], v);
        }
        T[(size_t)(m * NC + n) * D + d] = __float2half(v);
    }
}

// ---------------------------------------------------------------------------
// 8-lane all-reduce sum on the VALU via DPP (groups are 8-lane aligned).
// ---------------------------------------------------------------------------
__device__ __forceinline__ float grp8_allreduce_sum(float v) {
    int t;
    t = __builtin_amdgcn_update_dpp(0, __float_as_int(v), 0xB1, 0xF, 0xF, true);
    v += __int_as_float(t);
    t = __builtin_amdgcn_update_dpp(0, __float_as_int(v), 0x4E, 0xF, 0xF, true);
    v += __int_as_float(t);
    t = __builtin_amdgcn_update_dpp(0, __float_as_int(v), 0x141, 0xF, 0xF, true);
    v += __int_as_float(t);
    return v;
}

// ---------------------------------------------------------------------------
// Kernel 2: 8 lanes per item; proto in LDS; DPP reduce; fp16 T gather.
// SINGLE CHANGE vs round 16: T loads issued BEFORE the score/softmax chain
// (software prefetch into uint2 regs). theta -> m -> T addrs are independent
// of scores, so ~150 VALU cycles of score+reduce+softmax hide the L2 gather
// latency. Costs ~32 VGPR (occupancy 8->4 waves/SIMD) for 16x more MLP/wave.
// ---------------------------------------------------------------------------
__global__ __launch_bounds__(256) void mix_kernel8(
    const float* __restrict__ emb,
    const float* __restrict__ thetas,
    const float* __restrict__ proto,
    const __half* __restrict__ T,
    float* __restrict__ out_emb,
    float* __restrict__ out_P,
    int B)
{
    __shared__ float4 sproto[NC * (D / 4)];      // 2 KB
    if (threadIdx.x < NC * (D / 4)) {
        sproto[threadIdx.x] = ((const float4*)proto)[threadIdx.x];
    }
    __syncthreads();

    const int t = blockIdx.x * 256 + threadIdx.x;
    const int b = t >> 3;            // item index
    const int j = t & 7;             // lane-in-group
    if (b >= B) return;

    // --- theta -> minute bucket (first: unlocks T addresses) ---
    const float th = thetas[b];                  // broadcast within group
    int m = (int)((th / TWO_PI_F) * (float)NMIN);
    m = m < 0 ? 0 : (m > NMIN - 1 ? NMIN - 1 : m);

    // --- issue emb loads (independent of theta) ---
    const float4* __restrict__ e4 = (const float4*)emb + (size_t)b * (D / 4);
    const float4 ev0 = e4[j];
    const float4 ev1 = e4[j + 8];

    // --- PREFETCH: issue all 16 T loads now; consumed only after softmax ---
    const uint2* __restrict__ t2 = (const uint2*)(T + (size_t)m * NC * D);
    uint2 ua[NC], ub[NC];
#pragma unroll
    for (int n = 0; n < NC; ++n) {
        ua[n] = t2[n * 16 + j];
        ub[n] = t2[n * 16 + j + 8];
    }

    // --- partial scores vs 8 prototypes (from LDS; waits only on emb) ---
    float sc[NC];
#pragma unroll
    for (int n = 0; n < NC; ++n) {
        const float4 pa = sproto[n * (D / 4) + j];
        const float4 pb = sproto[n * (D / 4) + j + 8];
        float v = ev0.x * pa.x;
        v = fmaf(ev0.y, pa.y, v);
        v = fmaf(ev0.z, pa.z, v);
        v = fmaf(ev0.w, pa.w, v);
        v = fmaf(ev1.x, pb.x, v);
        v = fmaf(ev1.y, pb.y, v);
        v = fmaf(ev1.z, pb.z, v);
        v = fmaf(ev1.w, pb.w, v);
        sc[n] = v;
    }

    // --- reduce across the 8-lane group (VALU/DPP) ---
#pragma unroll
    for (int n = 0; n < NC; ++n) {
        sc[n] = grp8_allreduce_sum(sc[n]);
    }

    // --- softmax(scores / tau), tau = 0.2 -> *5 ---
    float mx = -1e30f;
#pragma unroll
    for (int n = 0; n < NC; ++n) { sc[n] *= 5.0f; mx = fmaxf(mx, sc[n]); }
    float sum = 0.0f;
#pragma unroll
    for (int n = 0; n < NC; ++n) { sc[n] = __expf(sc[n] - mx); sum += sc[n]; }
    const float inv = 1.0f / sum;
#pragma unroll
    for (int n = 0; n < NC; ++n) sc[n] *= inv;

    // --- unpack prefetched T and mix ---
    float4 acc0 = make_float4(0.f, 0.f, 0.f, 0.f);
    float4 acc1 = make_float4(0.f, 0.f, 0.f, 0.f);
#pragma unroll
    for (int n = 0; n < NC; ++n) {
        const float pw = sc[n];
        const float2 a01 = __half22float2(*(const __half2*)&ua[n].x);
        const float2 a23 = __half22float2(*(const __half2*)&ua[n].y);
        const float2 b01 = __half22float2(*(const __half2*)&ub[n].x);
        const float2 b23 = __half22float2(*(const __half2*)&ub[n].y);
        acc0.x = fmaf(pw, a01.x, acc0.x);
        acc0.y = fmaf(pw, a01.y, acc0.y);
        acc0.z = fmaf(pw, a23.x, acc0.z);
        acc0.w = fmaf(pw, a23.y, acc0.w);
        acc1.x = fmaf(pw, b01.x, acc1.x);
        acc1.y = fmaf(pw, b01.y, acc1.y);
        acc1.z = fmaf(pw, b23.x, acc1.z);
        acc1.w = fmaf(pw, b23.y, acc1.w);
    }

    float4* __restrict__ o4 = (float4*)out_emb + (size_t)b * (D / 4);
    o4[j]     = acc0;
    o4[j + 8] = acc1;

    // --- P output: lanes 0 and 4 each write one float4 ---
    if (j == 0) {
        ((float4*)out_P)[(size_t)b * 2 + 0] = make_float4(sc[0], sc[1], sc[2], sc[3]);
    } else if (j == 4) {
        ((float4*)out_P)[(size_t)b * 2 + 1] = make_float4(sc[4], sc[5], sc[6], sc[7]);
    }
}

// ---------------------------------------------------------------------------
// Fallback (only if ws_size too small): fully fused, coefficients in LDS.
// ---------------------------------------------------------------------------
__global__ __launch_bounds__(256) void fused_fallback(
    const float* __restrict__ emb,
    const float* __restrict__ thetas,
    const float* __restrict__ proto,
    const float* __restrict__ a0,
    const float* __restrict__ fa,
    const float* __restrict__ fb,
    float* __restrict__ out_emb,
    float* __restrict__ out_P,
    int B)
{
    __shared__ float sp[NC * D];
    __shared__ float sa0[NC * D];
    __shared__ float sfa[NC * FK * D];
    __shared__ float sfb[NC * FK * D];
    for (int i = threadIdx.x; i < NC * D; i += 256) { sp[i] = proto[i]; sa0[i] = a0[i]; }
    for (int i = threadIdx.x; i < NC * FK * D; i += 256) { sfa[i] = fa[i]; sfb[i] = fb[i]; }
    __syncthreads();

    const int b = blockIdx.x * 256 + threadIdx.x;
    if (b >= B) return;

    const float4* __restrict__ e4  = (const float4*)(emb + (size_t)b * D);
    const float4* sp4  = (const float4*)sp;
    const float4* sa04 = (const float4*)sa0;
    const float4* sfa4 = (const float4*)sfa;
    const float4* sfb4 = (const float4*)sfb;

    float sc[NC];
#pragma unroll
    for (int n = 0; n < NC; ++n) sc[n] = 0.0f;
#pragma unroll
    for (int i = 0; i < D / 4; ++i) {
        const float4 ev = e4[i];
#pragma unroll
        for (int n = 0; n < NC; ++n) {
            const float4 pv = sp4[n * (D / 4) + i];
            sc[n] = fmaf(ev.x, pv.x, sc[n]);
            sc[n] = fmaf(ev.y, pv.y, sc[n]);
            sc[n] = fmaf(ev.z, pv.z, sc[n]);
            sc[n] = fmaf(ev.w, pv.w, sc[n]);
        }
    }
    float mx = -1e30f;
#pragma unroll
    for (int n = 0; n < NC; ++n) { sc[n] *= 5.0f; mx = fmaxf(mx, sc[n]); }
    float sum = 0.0f;
#pragma unroll
    for (int n = 0; n < NC; ++n) { sc[n] = __expf(sc[n] - mx); sum += sc[n]; }
    const float inv = 1.0f / sum;
#pragma unroll
    for (int n = 0; n < NC; ++n) sc[n] *= inv;

    const float th = thetas[b];
    int m = (int)((th / TWO_PI_F) * (float)NMIN);
    m = m < 0 ? 0 : (m > NMIN - 1 ? NMIN - 1 : m);
    const float angle = (float)m * (TWO_PI_F / (float)(NMIN - 1));
    float c[FK], s[FK];
#pragma unroll
    for (int k = 0; k < FK; ++k) sincosf(angle * (float)(k + 1), &s[k], &c[k]);

    float4 acc[D / 4];
#pragma unroll
    for (int i = 0; i < D / 4; ++i) acc[i] = make_float4(0.f, 0.f, 0.f, 0.f);
#pragma unroll
    for (int n = 0; n < NC; ++n) {
        const float pw = sc[n];
#pragma unroll
        for (int i = 0; i < D / 4; ++i) {
            float4 v = sa04[n * (D / 4) + i];
#pragma unroll
            for (int k = 0; k < FK; ++k) {
                const float4 av = sfa4[(n * FK + k) * (D / 4) + i];
                const float4 bv = sfb4[(n * FK + k) * (D / 4) + i];
                v.x = fmaf(c[k], av.x, v.x); v.x = fmaf(s[k], bv.x, v.x);
                v.y = fmaf(c[k], av.y, v.y); v.y = fmaf(s[k], bv.y, v.y);
                v.z = fmaf(c[k], av.z, v.z); v.z = fmaf(s[k], bv.z, v.z);
                v.w = fmaf(c[k], av.w, v.w); v.w = fmaf(s[k], bv.w, v.w);
            }
            acc[i].x = fmaf(pw, v.x, acc[i].x);
            acc[i].y = fmaf(pw, v.y, acc[i].y);
            acc[i].z = fmaf(pw, v.z, acc[i].z);
            acc[i].w = fmaf(pw, v.w, acc[i].w);
        }
    }
    float4* o4 = (float4*)(out_emb + (size_t)b * D);
#pragma unroll
    for (int i = 0; i < D / 4; ++i) o4[i] = acc[i];
    float4* op = (float4*)(out_P + (size_t)b * NC);
    op[0] = make_float4(sc[0], sc[1], sc[2], sc[3]);
    op[1] = make_float4(sc[4], sc[5], sc[6], sc[7]);
}

extern "C" void kernel_launch(void* const* d_in, const int* in_sizes, int n_in,
                              void* d_out, int out_size, void* d_ws, size_t ws_size,
                              hipStream_t stream)
{
    const float* emb    = (const float*)d_in[0];
    const float* thetas = (const float*)d_in[1];
    const float* proto  = (const float*)d_in[2];
    const float* a0     = (const float*)d_in[3];
    const float* fa     = (const float*)d_in[4];
    const float* fb     = (const float*)d_in[5];

    const int B = in_sizes[0] / D;           // 131072
    float* out_emb = (float*)d_out;
    float* out_P   = (float*)d_out + (size_t)B * D;

    const size_t table_bytes = TSZ * sizeof(__half);   // ~1.5 MB

    if (ws_size >= table_bytes) {
        __half* T = (__half*)d_ws;
        build_table_kernel<<<NMIN, 256, 0, stream>>>(a0, fa, fb, T);
        // 8 lanes per item: B*8 threads total
        const long long total_threads = (long long)B * 8;
        const int blocks = (int)((total_threads + 255) / 256);
        mix_kernel8<<<blocks, 256, 0, stream>>>(emb, thetas, proto, T, out_emb, out_P, B);
    } else {
        const int blocks = (B + 255) / 256;
        fused_fallback<<<blocks, 256, 0, stream>>>(emb, thetas, proto, a0, fa, fb,
                                                   out_emb, out_P, B);
    }
}